// Round 5
// baseline (279.204 us; speedup 1.0000x reference)
//
#include <hip/hip_runtime.h>

namespace {

constexpr int D  = 64;    // channels per head
constexpr int T  = 2048;  // sequence length
constexpr int TQ = 64;    // queries per block
constexpr int NT = T / 64;
constexpr float SCL = 0.125f * 1.44269504088896340736f;  // scale^2 * log2(e)

// workspace layout (units: unsigned short):
//  [0, 64*32*8192)             KV tiles: (h*32+kt)*8192 ; K swizzled [s][c] first 4096, V [c][s] next 4096
//  [QP_OFF, QP_OFF+64*32*4096) Q tiles: (h*32+qt)*4096 swizzled [t][c], PRE-SCALED by SCL
constexpr size_t QP_OFF  = (size_t)64 * 32 * 8192;
constexpr size_t WS_NEED = ((size_t)64 * 32 * 8192 + (size_t)64 * 32 * 4096) * 2;  // 50331648 B

typedef __bf16 bf16x8 __attribute__((ext_vector_type(8)));
typedef float  f32x4  __attribute__((ext_vector_type(4)));
typedef unsigned short u16x4 __attribute__((ext_vector_type(4)));
typedef unsigned short u16x8 __attribute__((ext_vector_type(8)));
typedef unsigned int   u32x2 __attribute__((ext_vector_type(2)));

__device__ inline unsigned short f2bf(float f) {   // RNE fp32->bf16, finite inputs
    unsigned int u = __builtin_bit_cast(unsigned int, f);
    u += 0x7FFFu + ((u >> 16) & 1u);
    return (unsigned short)(u >> 16);
}

// pack two f32 -> packed bf16 pair (RNE); HW v_cvt_pk_bf16_f32 when available
__device__ inline unsigned int pkbf(float a, float b) {
#if __has_builtin(__builtin_amdgcn_cvt_pk_bf16_f32)
    auto r = __builtin_amdgcn_cvt_pk_bf16_f32(a, b);
    static_assert(sizeof(r) == 4, "cvt_pk_bf16 size");
    return __builtin_bit_cast(unsigned int, r);
#else
    return (unsigned int)f2bf(a) | ((unsigned int)f2bf(b) << 16);
#endif
}

// 64-wide rows, 16B granules XOR-swizzled by ((row>>1)&7): staging writes,
// b64 P writes and all b128 fragment reads stay at the 2-way (free) floor.
__device__ inline int frag_off(int row, int c0) {
    int g = (c0 >> 3) ^ ((row >> 1) & 7);
    return row * 64 + g * 8;
}

__device__ inline void async_cp16(const void* g, void* l) {
    __builtin_amdgcn_global_load_lds(
        (const __attribute__((address_space(1))) unsigned int*)g,
        (__attribute__((address_space(3))) unsigned int*)l, 16, 0, 0);
}

// ---------------- pre-pass: fp32 -> bf16, swizzled tiles, coalesced writes ----
// grid (32 tiles, 64 heads, 3): z=0 Q (transpose, pre-scaled), z=1 K (transpose),
// z=2 V (row copy). Q/K build the swizzled [t][c] image in LDS, then copy
// LDS->global linearly as 16B stores.
__global__ __launch_bounds__(256)
void prepass(const float* __restrict__ qkv, unsigned short* __restrict__ ws) {
    const int tile = blockIdx.x, h = blockIdx.y, z = blockIdx.z;
    const int tid = threadIdx.x;
    const float* src = qkv + (size_t)h * 3 * D * T + (size_t)z * D * T + tile * 64;
    __shared__ unsigned short L[4096];

    if (z == 2) {  // V: [c][s] granule-swizzled rows; 16B coalesced stores
        unsigned short* dst = ws + (size_t)(h * 32 + tile) * 8192 + 4096;
        #pragma unroll
        for (int half = 0; half < 2; half++) {
            int idx = half * 256 + tid;        // output granule 0..511
            int row = idx >> 3, g = idx & 7;
            int gg  = g ^ ((row >> 1) & 7);    // source granule
            f32x4 a = *(const f32x4*)(src + (size_t)row * T + gg * 8);
            f32x4 b = *(const f32x4*)(src + (size_t)row * T + gg * 8 + 4);
            u16x8 wv = { f2bf(a[0]), f2bf(a[1]), f2bf(a[2]), f2bf(a[3]),
                         f2bf(b[0]), f2bf(b[1]), f2bf(b[2]), f2bf(b[3]) };
            *(u16x8*)(dst + idx * 8) = wv;     // = dst + row*64 + g*8
        }
    } else {       // Q/K: transpose [c][t] -> swizzled [t][c] via LDS
        const float m = (z == 0) ? SCL : 1.0f;   // fold softmax scale into Q
        const int c0 = (tid >> 4) * 4, s4 = tid & 15;
        float fr[4][4];
        #pragma unroll
        for (int r = 0; r < 4; r++)
            *(f32x4*)fr[r] = *(const f32x4*)(src + (size_t)(c0 + r) * T + s4 * 4);
        #pragma unroll
        for (int j = 0; j < 4; j++) {
            int trow = s4 * 4 + j;
            u16x4 wv = { f2bf(fr[0][j] * m), f2bf(fr[1][j] * m),
                         f2bf(fr[2][j] * m), f2bf(fr[3][j] * m) };
            *(u16x4*)(L + frag_off(trow, c0) + (c0 & 7)) = wv;  // 2-way floor
        }
        __syncthreads();
        unsigned short* dst = (z == 0)
            ? ws + QP_OFF + (size_t)(h * 32 + tile) * 4096
            : ws + (size_t)(h * 32 + tile) * 8192;
        #pragma unroll
        for (int i = 0; i < 2; i++)   // linear image copy: conflict-free reads,
            *(u16x8*)(dst + tid * 16 + i * 8) =          // coalesced 16B stores
                *(const u16x8*)(L + tid * 16 + i * 8);
    }
}

// ---------------- main: flash attention, 16x16x32 bf16 MFMA ----------------
// Block = 4 waves. Wave w: sh=w&1 (s-half), th=w>>1 (t-half).
// SINGLE-buffer KV + 2 barriers/iter (m97 pattern): LDS 24 KB -> 6 blocks/CU
// (24 waves) — cross-block wave overlap hides the staging latency.
// All LDS fragment addresses precomputed (loop-invariant registers).
// P round-trip through LDS is wave-local (no barrier between S and PV).
__global__ __launch_bounds__(256, 6)
void attn_main(const unsigned short* __restrict__ ws, float* __restrict__ out) {
    const int h  = blockIdx.x;      // head pinned to XCD h%8; 8 heads * 512 KB = L2
    const int qt = blockIdx.y;
    const int t0 = qt * TQ;
    const int tid  = threadIdx.x;
    const int lane = tid & 63;
    const int w    = tid >> 6;
    const int sh   = w & 1, th = w >> 1;
    const int ln   = lane & 15, q4 = lane >> 4;

    __shared__ unsigned short KV[8192];   // [K 4096 | V 4096] single buffer
    __shared__ unsigned short Ps[4096];   // P^T staging, wave-disjoint granules
    // 24576 B -> 6 blocks/CU

    // Q fragments (loop-invariant, PRE-SCALED in prepass)
    const unsigned short* qtile = ws + QP_OFF + (size_t)(h * 32 + qt) * 4096;
    bf16x8 bQ[2][2];
    #pragma unroll
    for (int ti = 0; ti < 2; ti++)
        #pragma unroll
        for (int kc = 0; kc < 2; kc++) {
            int t = th * 32 + ti * 16 + ln;
            bQ[ti][kc] = *(const bf16x8*)(qtile + frag_off(t, kc * 32 + q4 * 8));
        }

    // ---- precompute every LDS address once ----
    const unsigned short* aKp[2][2];   // [kc][si]
    const unsigned short* aVp[4];      // [ci]
    const unsigned short* bPp[2];      // [ti]
    unsigned int*         pwp[2][2];   // [si][ti]
    {
        const unsigned short* Kr = &KV[0];
        const unsigned short* Vr = &KV[4096];
        #pragma unroll
        for (int kc = 0; kc < 2; kc++)
            #pragma unroll
            for (int si = 0; si < 2; si++)
                aKp[kc][si] = Kr + frag_off(sh * 32 + si * 16 + ln, kc * 32 + q4 * 8);
        #pragma unroll
        for (int ci = 0; ci < 4; ci++)
            aVp[ci] = Vr + frag_off(ci * 16 + ln, sh * 32 + q4 * 8);
        #pragma unroll
        for (int ti = 0; ti < 2; ti++) {
            bPp[ti] = Ps + frag_off(th * 32 + ti * 16 + ln, sh * 32 + q4 * 8);
            #pragma unroll
            for (int si = 0; si < 2; si++) {
                int t = th * 32 + ti * 16 + ln, c0p = sh * 32 + si * 16 + q4 * 4;
                pwp[si][ti] = (unsigned int*)(Ps + frag_off(t, c0p) + (c0p & 7));
            }
        }
    }
    char* stage = (char*)&KV[0] + w * 4096;
    const char* kvbase = (const char*)ws + (size_t)(h * 32) * 16384
                         + (size_t)w * 4096 + lane * 16;

    f32x4 acc_o[4][2];   // [ci][ti], partial over this wave's s-half
    #pragma unroll
    for (int ci = 0; ci < 4; ci++)
        #pragma unroll
        for (int ti = 0; ti < 2; ti++) acc_o[ci][ti] = (f32x4){0.f, 0.f, 0.f, 0.f};
    float l_acc[2] = {0.f, 0.f};

    #pragma unroll 1
    for (int kt = 0; kt < NT; kt++) {
        __syncthreads();   // (A) all waves done reading KV from previous iter
        {
            const char* gsrc = kvbase + (size_t)kt * 16384;
            #pragma unroll
            for (int i = 0; i < 4; i++) async_cp16(gsrc + i * 1024, stage + i * 1024);
        }
        __syncthreads();   // (B) vmcnt drained -> KV tile ready

        // ---- S^T[s-half][t-half]: 2x2 tiles x 2 k-chunks = 8 MFMAs ----
        f32x4 acc_s[2][2];
        #pragma unroll
        for (int si = 0; si < 2; si++)
            #pragma unroll
            for (int ti = 0; ti < 2; ti++) acc_s[si][ti] = (f32x4){0.f, 0.f, 0.f, 0.f};
        #pragma unroll
        for (int kc = 0; kc < 2; kc++)
            #pragma unroll
            for (int si = 0; si < 2; si++) {
                bf16x8 aK = *(const bf16x8*)aKp[kc][si];
                #pragma unroll
                for (int ti = 0; ti < 2; ti++)
                    acc_s[si][ti] = __builtin_amdgcn_mfma_f32_16x16x32_bf16(
                        aK, bQ[ti][kc], acc_s[si][ti], 0, 0, 0);
            }

        // ---- no-max softmax (Q pre-scaled): P = exp2(acc) directly ----
        // D-frag of S^T: col=ln -> t, row=q4*4+r -> s (4 consecutive s per lane)
        #pragma unroll
        for (int si = 0; si < 2; si++)
            #pragma unroll
            for (int ti = 0; ti < 2; ti++) {
                float p0 = __builtin_amdgcn_exp2f(acc_s[si][ti][0]);
                float p1 = __builtin_amdgcn_exp2f(acc_s[si][ti][1]);
                float p2 = __builtin_amdgcn_exp2f(acc_s[si][ti][2]);
                float p3 = __builtin_amdgcn_exp2f(acc_s[si][ti][3]);
                l_acc[ti] += (p0 + p1) + (p2 + p3);
                u32x2 pk = { pkbf(p0, p1), pkbf(p2, p3) };
                *(u32x2*)pwp[si][ti] = pk;      // b64, 2-way floor
            }

        // ---- PV: O_partial[64c][t-half] over this wave's s-half (k=32) ----
        // P written+read by the SAME wave: lgkmcnt ordering only, no barrier.
        bf16x8 bP0 = *(const bf16x8*)bPp[0];
        bf16x8 bP1 = *(const bf16x8*)bPp[1];
        #pragma unroll
        for (int ci = 0; ci < 4; ci++) {
            bf16x8 aV = *(const bf16x8*)aVp[ci];
            acc_o[ci][0] = __builtin_amdgcn_mfma_f32_16x16x32_bf16(
                aV, bP0, acc_o[ci][0], 0, 0, 0);
            acc_o[ci][1] = __builtin_amdgcn_mfma_f32_16x16x32_bf16(
                aV, bP1, acc_o[ci][1], 0, 0, 0);
        }
    }

    // ---- epilogue: merge s-half partials (O and l) via dead LDS ----
    __syncthreads();                      // all PV reads of KV/Ps done
    float* mrg = (float*)&KV[0];          // 16 KB: th*2048 floats per t-half
    float* lp  = (float*)Ps;
    #pragma unroll
    for (int ti = 0; ti < 2; ti++) {
        float s = l_acc[ti];
        s += __shfl_xor(s, 16, 64);
        s += __shfl_xor(s, 32, 64);
        if (q4 == 0) lp[th * 64 + sh * 32 + ti * 16 + ln] = s;
    }
    if (sh == 0) {
        float* base = mrg + th * 2048;
        #pragma unroll
        for (int ci = 0; ci < 4; ci++)
            #pragma unroll
            for (int ti = 0; ti < 2; ti++)
                *(f32x4*)(base + (ci * 2 + ti) * 256 + lane * 4) = acc_o[ci][ti];
    }
    __syncthreads();
    if (sh == 1) {
        float* base = mrg + th * 2048;
        float linv[2];
        #pragma unroll
        for (int ti = 0; ti < 2; ti++) {
            int tt = ti * 16 + ln;
            linv[ti] = 1.0f / (lp[th * 64 + tt] + lp[th * 64 + 32 + tt]);
        }
        float* ob = out + (size_t)h * D * T + t0 + th * 32;
        #pragma unroll
        for (int ci = 0; ci < 4; ci++)
            #pragma unroll
            for (int ti = 0; ti < 2; ti++) {
                f32x4 part = *(const f32x4*)(base + (ci * 2 + ti) * 256 + lane * 4);
                #pragma unroll
                for (int r = 0; r < 4; r++) {
                    int c = ci * 16 + q4 * 4 + r;
                    ob[(size_t)c * T + ti * 16 + ln] =
                        (acc_o[ci][ti][r] + part[r]) * linv[ti];
                }
            }
    }
}

// ---------------- fallback (R2 kernel, proven): used if ws too small ----------
__device__ inline bf16x8 frag8(const unsigned short* p, int row, int c0) {
    return *(const bf16x8*)(p + frag_off(row, c0));
}

__global__ __launch_bounds__(256)
void attn_fallback(const float* __restrict__ qkv, float* __restrict__ out) {
    const int h     = blockIdx.y;
    const int t0    = blockIdx.x * TQ;
    const int tid   = threadIdx.x;
    const int lane  = tid & 63;
    const int strip = tid >> 6;
    const int ln    = lane & 15;
    const int q4    = lane >> 4;

    __shared__ unsigned short Qs[TQ * D];
    __shared__ unsigned short Ks[64 * D];
    __shared__ unsigned short Vs[D * 64];
    __shared__ unsigned short Pss[TQ * 64];
    __shared__ float l_lds[TQ];

    const float* qb = qkv + (size_t)h * 3 * D * T;
    const float* kb = qb + (size_t)D * T;
    const float* vb = qb + (size_t)(2 * D) * T;
    const int s4 = tid & 15;
    const int c0 = (tid >> 4) * 4;
    {
        float fr[4][4];
        #pragma unroll
        for (int r = 0; r < 4; r++)
            *(f32x4*)fr[r] = *(const f32x4*)(qb + (size_t)(c0 + r) * T + t0 + s4 * 4);
        #pragma unroll
        for (int j = 0; j < 4; j++) {
            int trow = s4 * 4 + j;
            u16x4 wv = { f2bf(fr[0][j]), f2bf(fr[1][j]), f2bf(fr[2][j]), f2bf(fr[3][j]) };
            *(u16x4*)(Qs + frag_off(trow, c0) + (c0 & 7)) = wv;
        }
    }
    __syncthreads();
    const int arow = strip * 16 + ln;
    const int kg   = q4 * 8;
    const bf16x8 aq0 = frag8(Qs, arow, kg);
    const bf16x8 aq1 = frag8(Qs, arow, 32 + kg);
    f32x4 acc_o[4];
    #pragma unroll
    for (int m = 0; m < 4; m++) acc_o[m] = (f32x4){0.f, 0.f, 0.f, 0.f};
    float l_acc[4] = {0.f, 0.f, 0.f, 0.f};
    constexpr float S2 = 0.125f * 1.44269504088896340736f;
    for (int kt = 0; kt < NT; kt++) {
        const int s0 = kt * 64;
        float kr[4][4], vr[4][4];
        #pragma unroll
        for (int r = 0; r < 4; r++)
            *(f32x4*)kr[r] = *(const f32x4*)(kb + (size_t)(c0 + r) * T + s0 + s4 * 4);
        #pragma unroll
        for (int r = 0; r < 4; r++)
            *(f32x4*)vr[r] = *(const f32x4*)(vb + (size_t)(c0 + r) * T + s0 + s4 * 4);
        __syncthreads();
        #pragma unroll
        for (int j = 0; j < 4; j++) {
            int srow = s4 * 4 + j;
            u16x4 wk = { f2bf(kr[0][j]), f2bf(kr[1][j]), f2bf(kr[2][j]), f2bf(kr[3][j]) };
            *(u16x4*)(Ks + frag_off(srow, c0) + (c0 & 7)) = wk;
        }
        #pragma unroll
        for (int r = 0; r < 4; r++) {
            int row = c0 + r, cc = s4 * 4;
            u16x4 wv = { f2bf(vr[r][0]), f2bf(vr[r][1]), f2bf(vr[r][2]), f2bf(vr[r][3]) };
            *(u16x4*)(Vs + frag_off(row, cc) + (cc & 7)) = wv;
        }
        __syncthreads();
        f32x4 accs[4];
        #pragma unroll
        for (int ns = 0; ns < 4; ns++) {
            bf16x8 b0 = frag8(Ks, ns * 16 + ln, kg);
            bf16x8 b1 = frag8(Ks, ns * 16 + ln, 32 + kg);
            f32x4 z = {0.f, 0.f, 0.f, 0.f};
            z = __builtin_amdgcn_mfma_f32_16x16x32_bf16(aq0, b0, z, 0, 0, 0);
            z = __builtin_amdgcn_mfma_f32_16x16x32_bf16(aq1, b1, z, 0, 0, 0);
            accs[ns] = z;
        }
        #pragma unroll
        for (int ns = 0; ns < 4; ns++) {
            int scol = ns * 16 + ln;
            #pragma unroll
            for (int r = 0; r < 4; r++) {
                float p = __builtin_amdgcn_exp2f(accs[ns][r] * S2);
                l_acc[r] += p;
                int trow = strip * 16 + q4 * 4 + r;
                int g = ((scol >> 3) ^ ((trow >> 1) & 7));
                Pss[trow * 64 + g * 8 + (scol & 7)] = f2bf(p);
            }
        }
        bf16x8 bp0 = frag8(Pss, arow, kg);
        bf16x8 bp1 = frag8(Pss, arow, 32 + kg);
        #pragma unroll
        for (int ms = 0; ms < 4; ms++) {
            bf16x8 av0 = frag8(Vs, ms * 16 + ln, kg);
            bf16x8 av1 = frag8(Vs, ms * 16 + ln, 32 + kg);
            acc_o[ms] = __builtin_amdgcn_mfma_f32_16x16x32_bf16(av0, bp0, acc_o[ms], 0, 0, 0);
            acc_o[ms] = __builtin_amdgcn_mfma_f32_16x16x32_bf16(av1, bp1, acc_o[ms], 0, 0, 0);
        }
    }
    #pragma unroll
    for (int r = 0; r < 4; r++) {
        float s = l_acc[r];
        s += __shfl_xor(s, 1, 64);
        s += __shfl_xor(s, 2, 64);
        s += __shfl_xor(s, 4, 64);
        s += __shfl_xor(s, 8, 64);
        if (ln == 0) l_lds[strip * 16 + q4 * 4 + r] = s;
    }
    const float linv = 1.0f / l_lds[strip * 16 + ln];
    const int tg = t0 + strip * 16 + ln;
    float* ob = out + (size_t)h * D * T;
    #pragma unroll
    for (int ms = 0; ms < 4; ms++)
        #pragma unroll
        for (int r = 0; r < 4; r++) {
            int c = ms * 16 + q4 * 4 + r;
            ob[(size_t)c * T + tg] = acc_o[ms][r] * linv;
        }
}

} // namespace

extern "C" void kernel_launch(void* const* d_in, const int* in_sizes, int n_in,
                              void* d_out, int out_size, void* d_ws, size_t ws_size,
                              hipStream_t stream) {
    const float* qkv = (const float*)d_in[0];
    float* out = (float*)d_out;
    if (ws_size >= WS_NEED) {
        prepass<<<dim3(32, 64, 3), 256, 0, stream>>>(qkv, (unsigned short*)d_ws);
        attn_main<<<dim3(64, 32), 256, 0, stream>>>((const unsigned short*)d_ws, out);
    } else {
        attn_fallback<<<dim3(32, 64), 256, 0, stream>>>(qkv, out);
    }
}

// Round 6
// 257.914 us; speedup vs baseline: 1.0825x; 1.0825x over previous
//
#include <hip/hip_runtime.h>

namespace {

constexpr int D  = 64;    // channels per head
constexpr int T  = 2048;  // sequence length
constexpr int TQ = 64;    // queries per block
constexpr int NT = T / 64;
constexpr float SCL = 0.125f * 1.44269504088896340736f;  // scale^2 * log2(e)

// workspace layout (units: unsigned short):
//  [0, 64*32*8192)             KV tiles: (h*32+kt)*8192 ; K swizzled [s][c] first 4096, V [c][s] next 4096
//  [QP_OFF, QP_OFF+64*32*4096) Q tiles: (h*32+qt)*4096 swizzled [t][c], PRE-SCALED by SCL
constexpr size_t QP_OFF  = (size_t)64 * 32 * 8192;
constexpr size_t WS_NEED = ((size_t)64 * 32 * 8192 + (size_t)64 * 32 * 4096) * 2;  // 50331648 B

typedef __bf16 bf16x8 __attribute__((ext_vector_type(8)));
typedef float  f32x4  __attribute__((ext_vector_type(4)));
typedef unsigned short u16x4 __attribute__((ext_vector_type(4)));
typedef unsigned short u16x8 __attribute__((ext_vector_type(8)));
typedef unsigned int   u32x2 __attribute__((ext_vector_type(2)));

__device__ inline unsigned short f2bf(float f) {   // RNE fp32->bf16, finite inputs
    unsigned int u = __builtin_bit_cast(unsigned int, f);
    u += 0x7FFFu + ((u >> 16) & 1u);
    return (unsigned short)(u >> 16);
}

__device__ inline unsigned int pkbf(float a, float b) {
#if __has_builtin(__builtin_amdgcn_cvt_pk_bf16_f32)
    auto r = __builtin_amdgcn_cvt_pk_bf16_f32(a, b);
    static_assert(sizeof(r) == 4, "cvt_pk_bf16 size");
    return __builtin_bit_cast(unsigned int, r);
#else
    return (unsigned int)f2bf(a) | ((unsigned int)f2bf(b) << 16);
#endif
}

// 64-wide rows, 16B granules XOR-swizzled by ((row>>1)&7): staging writes,
// b64 P writes and all b128 fragment reads stay at the 2-way (free) floor.
__device__ inline int frag_off(int row, int c0) {
    int g = (c0 >> 3) ^ ((row >> 1) & 7);
    return row * 64 + g * 8;
}

__device__ inline void async_cp16(const void* g, void* l) {
    __builtin_amdgcn_global_load_lds(
        (const __attribute__((address_space(1))) unsigned int*)g,
        (__attribute__((address_space(3))) unsigned int*)l, 16, 0, 0);
}

// ---------------- pre-pass: fp32 -> bf16, swizzled tiles, coalesced writes ----
__global__ __launch_bounds__(256)
void prepass(const float* __restrict__ qkv, unsigned short* __restrict__ ws) {
    const int tile = blockIdx.x, h = blockIdx.y, z = blockIdx.z;
    const int tid = threadIdx.x;
    const float* src = qkv + (size_t)h * 3 * D * T + (size_t)z * D * T + tile * 64;
    __shared__ unsigned short L[4096];

    if (z == 2) {  // V: [c][s] granule-swizzled rows; 16B coalesced stores
        unsigned short* dst = ws + (size_t)(h * 32 + tile) * 8192 + 4096;
        #pragma unroll
        for (int half = 0; half < 2; half++) {
            int idx = half * 256 + tid;        // output granule 0..511
            int row = idx >> 3, g = idx & 7;
            int gg  = g ^ ((row >> 1) & 7);    // source granule
            f32x4 a = *(const f32x4*)(src + (size_t)row * T + gg * 8);
            f32x4 b = *(const f32x4*)(src + (size_t)row * T + gg * 8 + 4);
            u16x8 wv = { f2bf(a[0]), f2bf(a[1]), f2bf(a[2]), f2bf(a[3]),
                         f2bf(b[0]), f2bf(b[1]), f2bf(b[2]), f2bf(b[3]) };
            *(u16x8*)(dst + idx * 8) = wv;     // = dst + row*64 + g*8
        }
    } else {       // Q/K: transpose [c][t] -> swizzled [t][c] via LDS
        const float m = (z == 0) ? SCL : 1.0f;   // fold softmax scale into Q
        const int c0 = (tid >> 4) * 4, s4 = tid & 15;
        float fr[4][4];
        #pragma unroll
        for (int r = 0; r < 4; r++)
            *(f32x4*)fr[r] = *(const f32x4*)(src + (size_t)(c0 + r) * T + s4 * 4);
        #pragma unroll
        for (int j = 0; j < 4; j++) {
            int trow = s4 * 4 + j;
            u16x4 wv = { f2bf(fr[0][j] * m), f2bf(fr[1][j] * m),
                         f2bf(fr[2][j] * m), f2bf(fr[3][j] * m) };
            *(u16x4*)(L + frag_off(trow, c0) + (c0 & 7)) = wv;
        }
        __syncthreads();
        unsigned short* dst = (z == 0)
            ? ws + QP_OFF + (size_t)(h * 32 + tile) * 4096
            : ws + (size_t)(h * 32 + tile) * 8192;
        #pragma unroll
        for (int i = 0; i < 2; i++)
            *(u16x8*)(dst + tid * 16 + i * 8) = *(const u16x8*)(L + tid * 16 + i * 8);
    }
}

// ---------------- main: pipelined flash attention, 16x16x32 bf16 MFMA ----------
// Block = 4 waves. Wave w: sh=w&1 (s-half), th=w>>1 (t-half).
// Software pipeline: iter J computes S_J and PV_{J-1} back-to-back (16
// independent MFMAs) before exp_J. K double-buffered; V prefetch lags K by one
// tile so V also fits a double buffer despite its 2-iteration lifetime.
// P_J is written after PV_{J-1} reads Ps (same-wave DS ops are in-order ->
// no barrier). One barrier per iteration. LDS 40 KB -> 4 blocks/CU.

#define STAGE_K(J, B)                                                         \
  { const char* g = kvb + (size_t)(J) * 16384;                                \
    async_cp16(g,        kst[B]);                                             \
    async_cp16(g + 1024, kst[B] + 1024); }
#define STAGE_V(J, B)                                                         \
  { const char* g = kvb + (size_t)(J) * 16384 + 8192;                         \
    async_cp16(g,        vst[B]);                                             \
    async_cp16(g + 1024, vst[B] + 1024); }

// S_J on kbuf[B]; optional PV_{J-1} on vbuf[B^1]; exp_J; P_J write.
#define S_PHASE(B)                                                            \
    f32x4 acc_s[2][2];                                                        \
    _Pragma("unroll")                                                         \
    for (int si = 0; si < 2; si++) {                                          \
      bf16x8 aK0 = *(const bf16x8*)aKp[B][0][si];                             \
      _Pragma("unroll")                                                       \
      for (int ti = 0; ti < 2; ti++)                                          \
        acc_s[si][ti] = __builtin_amdgcn_mfma_f32_16x16x32_bf16(              \
            aK0, bQ[ti][0], ZF, 0, 0, 0);                                     \
    }                                                                         \
    _Pragma("unroll")                                                         \
    for (int si = 0; si < 2; si++) {                                          \
      bf16x8 aK1 = *(const bf16x8*)aKp[B][1][si];                             \
      _Pragma("unroll")                                                       \
      for (int ti = 0; ti < 2; ti++)                                          \
        acc_s[si][ti] = __builtin_amdgcn_mfma_f32_16x16x32_bf16(              \
            aK1, bQ[ti][1], acc_s[si][ti], 0, 0, 0);                          \
    }

#define PV_PHASE(VB)                                                          \
    { bf16x8 bP0 = *(const bf16x8*)bPp[0];                                    \
      bf16x8 bP1 = *(const bf16x8*)bPp[1];                                    \
      _Pragma("unroll")                                                       \
      for (int ci = 0; ci < 4; ci++) {                                        \
        bf16x8 aV = *(const bf16x8*)aVp[VB][ci];                              \
        acc_o[ci][0] = __builtin_amdgcn_mfma_f32_16x16x32_bf16(               \
            aV, bP0, acc_o[ci][0], 0, 0, 0);                                  \
        acc_o[ci][1] = __builtin_amdgcn_mfma_f32_16x16x32_bf16(               \
            aV, bP1, acc_o[ci][1], 0, 0, 0);                                  \
      } }

#define EXP_P()                                                               \
    _Pragma("unroll")                                                         \
    for (int si = 0; si < 2; si++)                                            \
      _Pragma("unroll")                                                       \
      for (int ti = 0; ti < 2; ti++) {                                        \
        float p0 = __builtin_amdgcn_exp2f(acc_s[si][ti][0]);                  \
        float p1 = __builtin_amdgcn_exp2f(acc_s[si][ti][1]);                  \
        float p2 = __builtin_amdgcn_exp2f(acc_s[si][ti][2]);                  \
        float p3 = __builtin_amdgcn_exp2f(acc_s[si][ti][3]);                  \
        l_acc[ti] += (p0 + p1) + (p2 + p3);                                   \
        u32x2 pk = { pkbf(p0, p1), pkbf(p2, p3) };                            \
        *(u32x2*)pwp[si][ti] = pk;                                            \
      }

__global__ __launch_bounds__(256, 4)
void attn_main(const unsigned short* __restrict__ ws, float* __restrict__ out) {
    const int h  = blockIdx.x;      // head pinned to XCD h%8; 8 heads * 512 KB = L2
    const int qt = blockIdx.y;
    const int t0 = qt * TQ;
    const int tid  = threadIdx.x;
    const int lane = tid & 63;
    const int w    = tid >> 6;
    const int sh   = w & 1, th = w >> 1;
    const int ln   = lane & 15, q4 = lane >> 4;

    __shared__ unsigned short Kb[2][4096];  // K tiles [s][c] swizzled (8 KB each)
    __shared__ unsigned short Vb[2][4096];  // V tiles [c][s] swizzled
    __shared__ unsigned short Ps[4096];     // P^T (t x s), wave-disjoint granules
    // 40960 B -> 4 blocks/CU

    // Q fragments (loop-invariant, PRE-SCALED in prepass)
    const unsigned short* qtile = ws + QP_OFF + (size_t)(h * 32 + qt) * 4096;
    bf16x8 bQ[2][2];
    #pragma unroll
    for (int ti = 0; ti < 2; ti++)
        #pragma unroll
        for (int kc = 0; kc < 2; kc++) {
            int t = th * 32 + ti * 16 + ln;
            bQ[ti][kc] = *(const bf16x8*)(qtile + frag_off(t, kc * 32 + q4 * 8));
        }

    // ---- precompute every LDS address once ----
    const unsigned short* aKp[2][2][2];   // [buf][kc][si]
    const unsigned short* aVp[2][4];      // [buf][ci]
    const unsigned short* bPp[2];         // [ti]
    unsigned int*         pwp[2][2];      // [si][ti]
    char *kst[2], *vst[2];
    #pragma unroll
    for (int b = 0; b < 2; b++) {
        #pragma unroll
        for (int kc = 0; kc < 2; kc++)
            #pragma unroll
            for (int si = 0; si < 2; si++)
                aKp[b][kc][si] = &Kb[b][0] + frag_off(sh * 32 + si * 16 + ln, kc * 32 + q4 * 8);
        #pragma unroll
        for (int ci = 0; ci < 4; ci++)
            aVp[b][ci] = &Vb[b][0] + frag_off(ci * 16 + ln, sh * 32 + q4 * 8);
        kst[b] = (char*)&Kb[b][0] + w * 2048;
        vst[b] = (char*)&Vb[b][0] + w * 2048;
    }
    #pragma unroll
    for (int ti = 0; ti < 2; ti++) {
        bPp[ti] = Ps + frag_off(th * 32 + ti * 16 + ln, sh * 32 + q4 * 8);
        #pragma unroll
        for (int si = 0; si < 2; si++) {
            int t = th * 32 + ti * 16 + ln, c0p = sh * 32 + si * 16 + q4 * 4;
            pwp[si][ti] = (unsigned int*)(Ps + frag_off(t, c0p) + (c0p & 7));
        }
    }
    const char* kvb = (const char*)ws + (size_t)(h * 32) * 16384
                      + (size_t)w * 2048 + lane * 16;
    const f32x4 ZF = {0.f, 0.f, 0.f, 0.f};

    f32x4 acc_o[4][2];   // [ci][ti], partial over this wave's s-half
    #pragma unroll
    for (int ci = 0; ci < 4; ci++)
        #pragma unroll
        for (int ti = 0; ti < 2; ti++) acc_o[ci][ti] = ZF;
    float l_acc[2] = {0.f, 0.f};

    // ---- prologue: stage K_0; iter 0 (no PV) ----
    STAGE_K(0, 0)
    __syncthreads();                // K_0 ready
    STAGE_K(1, 1) STAGE_V(0, 0)
    {
        S_PHASE(0)
        EXP_P()
    }

    // ---- steady state: J = 1..30 in parity pairs ----
    #pragma unroll 1
    for (int m = 0; m < 15; m++) {
        const int j = 2 * m + 1;
        {   // J odd, B=1
            __syncthreads();        // K_J, V_{J-1} ready; prev bufs free
            STAGE_K(j + 1, 0) STAGE_V(j, 1)
            S_PHASE(1)
            PV_PHASE(0)
            EXP_P()
        }
        {   // J even, B=0
            __syncthreads();
            STAGE_K(j + 2, 1) STAGE_V(j + 1, 0)
            S_PHASE(0)
            PV_PHASE(1)
            EXP_P()
        }
    }

    // ---- J = 31 (B=1): no K-stage ----
    {
        __syncthreads();
        STAGE_V(31, 1)
        S_PHASE(1)
        PV_PHASE(0)
        EXP_P()
    }
    // ---- drain: PV_31 ----
    __syncthreads();                // V_31 ready
    PV_PHASE(1)

    // ---- epilogue: merge s-half partials (O and l) via dead LDS ----
    __syncthreads();
    float* mrg = (float*)&Kb[0][0];       // 16 KB scratch
    float* lp  = (float*)Ps;
    #pragma unroll
    for (int ti = 0; ti < 2; ti++) {
        float s = l_acc[ti];
        s += __shfl_xor(s, 16, 64);
        s += __shfl_xor(s, 32, 64);
        if (q4 == 0) lp[th * 64 + sh * 32 + ti * 16 + ln] = s;
    }
    if (sh == 0) {
        float* base = mrg + th * 2048;
        #pragma unroll
        for (int ci = 0; ci < 4; ci++)
            #pragma unroll
            for (int ti = 0; ti < 2; ti++)
                *(f32x4*)(base + (ci * 2 + ti) * 256 + lane * 4) = acc_o[ci][ti];
    }
    __syncthreads();
    if (sh == 1) {
        float* base = mrg + th * 2048;
        float linv[2];
        #pragma unroll
        for (int ti = 0; ti < 2; ti++) {
            int tt = ti * 16 + ln;
            linv[ti] = 1.0f / (lp[th * 64 + tt] + lp[th * 64 + 32 + tt]);
        }
        float* ob = out + (size_t)h * D * T + t0 + th * 32;
        #pragma unroll
        for (int ci = 0; ci < 4; ci++)
            #pragma unroll
            for (int ti = 0; ti < 2; ti++) {
                f32x4 part = *(const f32x4*)(base + (ci * 2 + ti) * 256 + lane * 4);
                #pragma unroll
                for (int r = 0; r < 4; r++) {
                    int c = ci * 16 + q4 * 4 + r;
                    ob[(size_t)c * T + ti * 16 + ln] =
                        (acc_o[ci][ti][r] + part[r]) * linv[ti];
                }
            }
    }
}

// ---------------- fallback (R2 kernel, proven): used if ws too small ----------
__device__ inline bf16x8 frag8(const unsigned short* p, int row, int c0) {
    return *(const bf16x8*)(p + frag_off(row, c0));
}

__global__ __launch_bounds__(256)
void attn_fallback(const float* __restrict__ qkv, float* __restrict__ out) {
    const int h     = blockIdx.y;
    const int t0    = blockIdx.x * TQ;
    const int tid   = threadIdx.x;
    const int lane  = tid & 63;
    const int strip = tid >> 6;
    const int ln    = lane & 15;
    const int q4    = lane >> 4;

    __shared__ unsigned short Qs[TQ * D];
    __shared__ unsigned short Ks[64 * D];
    __shared__ unsigned short Vs[D * 64];
    __shared__ unsigned short Pss[TQ * 64];
    __shared__ float l_lds[TQ];

    const float* qb = qkv + (size_t)h * 3 * D * T;
    const float* kb = qb + (size_t)D * T;
    const float* vb = qb + (size_t)(2 * D) * T;
    const int s4 = tid & 15;
    const int c0 = (tid >> 4) * 4;
    {
        float fr[4][4];
        #pragma unroll
        for (int r = 0; r < 4; r++)
            *(f32x4*)fr[r] = *(const f32x4*)(qb + (size_t)(c0 + r) * T + t0 + s4 * 4);
        #pragma unroll
        for (int j = 0; j < 4; j++) {
            int trow = s4 * 4 + j;
            u16x4 wv = { f2bf(fr[0][j]), f2bf(fr[1][j]), f2bf(fr[2][j]), f2bf(fr[3][j]) };
            *(u16x4*)(Qs + frag_off(trow, c0) + (c0 & 7)) = wv;
        }
    }
    __syncthreads();
    const int arow = strip * 16 + ln;
    const int kg   = q4 * 8;
    const bf16x8 aq0 = frag8(Qs, arow, kg);
    const bf16x8 aq1 = frag8(Qs, arow, 32 + kg);
    f32x4 acc_o[4];
    #pragma unroll
    for (int m = 0; m < 4; m++) acc_o[m] = (f32x4){0.f, 0.f, 0.f, 0.f};
    float l_acc[4] = {0.f, 0.f, 0.f, 0.f};
    constexpr float S2 = 0.125f * 1.44269504088896340736f;
    for (int kt = 0; kt < NT; kt++) {
        const int s0 = kt * 64;
        float kr[4][4], vr[4][4];
        #pragma unroll
        for (int r = 0; r < 4; r++)
            *(f32x4*)kr[r] = *(const f32x4*)(kb + (size_t)(c0 + r) * T + s0 + s4 * 4);
        #pragma unroll
        for (int r = 0; r < 4; r++)
            *(f32x4*)vr[r] = *(const f32x4*)(vb + (size_t)(c0 + r) * T + s0 + s4 * 4);
        __syncthreads();
        #pragma unroll
        for (int j = 0; j < 4; j++) {
            int srow = s4 * 4 + j;
            u16x4 wk = { f2bf(kr[0][j]), f2bf(kr[1][j]), f2bf(kr[2][j]), f2bf(kr[3][j]) };
            *(u16x4*)(Ks + frag_off(srow, c0) + (c0 & 7)) = wk;
        }
        #pragma unroll
        for (int r = 0; r < 4; r++) {
            int row = c0 + r, cc = s4 * 4;
            u16x4 wv = { f2bf(vr[r][0]), f2bf(vr[r][1]), f2bf(vr[r][2]), f2bf(vr[r][3]) };
            *(u16x4*)(Vs + frag_off(row, cc) + (cc & 7)) = wv;
        }
        __syncthreads();
        f32x4 accs[4];
        #pragma unroll
        for (int ns = 0; ns < 4; ns++) {
            bf16x8 b0 = frag8(Ks, ns * 16 + ln, kg);
            bf16x8 b1 = frag8(Ks, ns * 16 + ln, 32 + kg);
            f32x4 z = {0.f, 0.f, 0.f, 0.f};
            z = __builtin_amdgcn_mfma_f32_16x16x32_bf16(aq0, b0, z, 0, 0, 0);
            z = __builtin_amdgcn_mfma_f32_16x16x32_bf16(aq1, b1, z, 0, 0, 0);
            accs[ns] = z;
        }
        #pragma unroll
        for (int ns = 0; ns < 4; ns++) {
            int scol = ns * 16 + ln;
            #pragma unroll
            for (int r = 0; r < 4; r++) {
                float p = __builtin_amdgcn_exp2f(accs[ns][r] * S2);
                l_acc[r] += p;
                int trow = strip * 16 + q4 * 4 + r;
                int g = ((scol >> 3) ^ ((trow >> 1) & 7));
                Pss[trow * 64 + g * 8 + (scol & 7)] = f2bf(p);
            }
        }
        bf16x8 bp0 = frag8(Pss, arow, kg);
        bf16x8 bp1 = frag8(Pss, arow, 32 + kg);
        #pragma unroll
        for (int ms = 0; ms < 4; ms++) {
            bf16x8 av0 = frag8(Vs, ms * 16 + ln, kg);
            bf16x8 av1 = frag8(Vs, ms * 16 + ln, 32 + kg);
            acc_o[ms] = __builtin_amdgcn_mfma_f32_16x16x32_bf16(av0, bp0, acc_o[ms], 0, 0, 0);
            acc_o[ms] = __builtin_amdgcn_mfma_f32_16x16x32_bf16(av1, bp1, acc_o[ms], 0, 0, 0);
        }
    }
    #pragma unroll
    for (int r = 0; r < 4; r++) {
        float s = l_acc[r];
        s += __shfl_xor(s, 1, 64);
        s += __shfl_xor(s, 2, 64);
        s += __shfl_xor(s, 4, 64);
        s += __shfl_xor(s, 8, 64);
        if (ln == 0) l_lds[strip * 16 + q4 * 4 + r] = s;
    }
    const float linv = 1.0f / l_lds[strip * 16 + ln];
    const int tg = t0 + strip * 16 + ln;
    float* ob = out + (size_t)h * D * T;
    #pragma unroll
    for (int ms = 0; ms < 4; ms++)
        #pragma unroll
        for (int r = 0; r < 4; r++) {
            int c = ms * 16 + q4 * 4 + r;
            ob[(size_t)c * T + tg] = acc_o[ms][r] * linv;
        }
}

} // namespace

extern "C" void kernel_launch(void* const* d_in, const int* in_sizes, int n_in,
                              void* d_out, int out_size, void* d_ws, size_t ws_size,
                              hipStream_t stream) {
    const float* qkv = (const float*)d_in[0];
    float* out = (float*)d_out;
    if (ws_size >= WS_NEED) {
        prepass<<<dim3(32, 64, 3), 256, 0, stream>>>(qkv, (unsigned short*)d_ws);
        attn_main<<<dim3(64, 32), 256, 0, stream>>>((const unsigned short*)d_ws, out);
    } else {
        attn_fallback<<<dim3(32, 64), 256, 0, stream>>>(qkv, out);
    }
}